// Round 1
// baseline (13837.047 us; speedup 1.0000x reference)
//
#include <hip/hip_runtime.h>
#include <math.h>

#define HH   50     // real hidden size
#define HP   64     // padded hidden size
#define GP   256    // padded gate count (4*HP)
#define TT   512    // sequence length
#define BB   8      // batch rows per block
#define NOUT 4
#define NTHR 256
#define NUPD (BB * HP / NTHR)   // update units per thread per layer = 2

__device__ __forceinline__ float rcp_f(float x) { return __builtin_amdgcn_rcpf(x); }
__device__ __forceinline__ float sigm_f(float x) { return rcp_f(1.0f + __expf(-x)); }
__device__ __forceinline__ float tanh_fast(float x) {
    float ax = fabsf(x);
    float e  = __expf(-2.0f * ax);
    float r  = (1.0f - e) * rcp_f(1.0f + e);
    return copysignf(r, x);
}

__global__ __launch_bounds__(NTHR, 2) void lstm2_persistent(
    const float* __restrict__ x,      // [B, T]
    const float* __restrict__ W_ih0,  // [200, 1]
    const float* __restrict__ W_hh0,  // [200, 50]
    const float* __restrict__ b_ih0,  // [200]
    const float* __restrict__ b_hh0,  // [200]
    const float* __restrict__ W_ih1,  // [200, 50]
    const float* __restrict__ W_hh1,  // [200, 50]
    const float* __restrict__ b_ih1,  // [200]
    const float* __restrict__ b_hh1,  // [200]
    const float* __restrict__ W_fc,   // [4, 50]
    const float* __restrict__ b_fc,   // [4]
    float* __restrict__ out)          // [B, 4]
{
    __shared__ float x_lds[TT][BB];     // 16 KB
    __shared__ float gates[BB][GP];     //  8 KB
    __shared__ float h0[BB][HP];        //  2 KB
    __shared__ float h1[BB][HP];        //  2 KB

    const int tid = threadIdx.x;
    const int b0  = blockIdx.x * BB;

    // ---- stage x for our batch rows: x_lds[t][b] (coalesced along t) ----
    for (int i = tid; i < TT * BB; i += NTHR) {
        int bi = i / TT;
        int ti = i % TT;
        x_lds[ti][bi] = x[(size_t)(b0 + bi) * TT + ti];
    }
    // ---- init h to zero ----
    for (int i = tid; i < BB * HP; i += NTHR) {
        (&h0[0][0])[i] = 0.0f;
        (&h1[0][0])[i] = 0.0f;
    }

    // ---- load this thread's gate-row weights into registers ----
    // padded gate row p = tid: type = tid>>6 (i,f,g,o), unit j = tid&63.
    const int type = tid >> 6;
    const int j    = tid & 63;

    float w0[52], wi1[52], w1[52];   // k padded 50 -> 52 (float4 granularity)
    float wx0 = 0.0f, bias0 = 0.0f, bias1 = 0.0f;
#pragma unroll
    for (int k = 0; k < 52; ++k) { w0[k] = 0.0f; wi1[k] = 0.0f; w1[k] = 0.0f; }
    if (j < HH) {
        const int g = type * HH + j;   // real gate row index
#pragma unroll
        for (int k = 0; k < HH; ++k) {
            w0[k]  = W_hh0[g * HH + k];
            wi1[k] = W_ih1[g * HH + k];
            w1[k]  = W_hh1[g * HH + k];
        }
        wx0   = W_ih0[g];
        bias0 = b_ih0[g] + b_hh0[g];
        bias1 = b_ih1[g] + b_hh1[g];
    }

    // ---- cell state (update-owner thread r: unit lin = r*NTHR + tid) ----
    float c0r[NUPD], c1r[NUPD];
#pragma unroll
    for (int r = 0; r < NUPD; ++r) { c0r[r] = 0.0f; c1r[r] = 0.0f; }

    __syncthreads();

    for (int t = 0; t < TT; ++t) {
        // ======== layer 0: gate pre-activations ========
#pragma unroll 2
        for (int b = 0; b < BB; ++b) {
            float xt  = x_lds[t][b];
            const float4* hv = (const float4*)&h0[b][0];
            float4 a = make_float4(0.f, 0.f, 0.f, 0.f);
#pragma unroll
            for (int k4 = 0; k4 < 13; ++k4) {
                float4 hh = hv[k4];                 // broadcast read
                a.x = fmaf(w0[4 * k4 + 0], hh.x, a.x);
                a.y = fmaf(w0[4 * k4 + 1], hh.y, a.y);
                a.z = fmaf(w0[4 * k4 + 2], hh.z, a.z);
                a.w = fmaf(w0[4 * k4 + 3], hh.w, a.w);
            }
            gates[b][tid] = bias0 + wx0 * xt + ((a.x + a.y) + (a.z + a.w));
        }
        __syncthreads();

        // ======== layer 0: pointwise update ========
#pragma unroll
        for (int r = 0; r < NUPD; ++r) {
            int lin = r * NTHR + tid;
            int b   = lin >> 6;
            int jj  = lin & 63;
            float gi = gates[b][jj];
            float gf = gates[b][64 + jj];
            float gg = gates[b][128 + jj];
            float go = gates[b][192 + jj];
            float i_ = sigm_f(gi);
            float f_ = sigm_f(gf);
            float g_ = tanh_fast(gg);
            float o_ = sigm_f(go);
            float c  = fmaf(f_, c0r[r], i_ * g_);
            c0r[r]   = c;
            h0[b][jj] = o_ * tanh_fast(c);
        }
        __syncthreads();

        // ======== layer 1: gate pre-activations (input = h0, state = h1) ========
#pragma unroll 2
        for (int b = 0; b < BB; ++b) {
            const float4* hav = (const float4*)&h0[b][0];
            const float4* hbv = (const float4*)&h1[b][0];
            float4 a = make_float4(0.f, 0.f, 0.f, 0.f);
#pragma unroll
            for (int k4 = 0; k4 < 13; ++k4) {
                float4 ha = hav[k4];                // broadcast read
                float4 hb = hbv[k4];                // broadcast read
                a.x = fmaf(wi1[4 * k4 + 0], ha.x, a.x);
                a.y = fmaf(wi1[4 * k4 + 1], ha.y, a.y);
                a.z = fmaf(wi1[4 * k4 + 2], ha.z, a.z);
                a.w = fmaf(wi1[4 * k4 + 3], ha.w, a.w);
                a.x = fmaf(w1[4 * k4 + 0], hb.x, a.x);
                a.y = fmaf(w1[4 * k4 + 1], hb.y, a.y);
                a.z = fmaf(w1[4 * k4 + 2], hb.z, a.z);
                a.w = fmaf(w1[4 * k4 + 3], hb.w, a.w);
            }
            gates[b][tid] = bias1 + ((a.x + a.y) + (a.z + a.w));
        }
        __syncthreads();

        // ======== layer 1: pointwise update ========
#pragma unroll
        for (int r = 0; r < NUPD; ++r) {
            int lin = r * NTHR + tid;
            int b   = lin >> 6;
            int jj  = lin & 63;
            float gi = gates[b][jj];
            float gf = gates[b][64 + jj];
            float gg = gates[b][128 + jj];
            float go = gates[b][192 + jj];
            float i_ = sigm_f(gi);
            float f_ = sigm_f(gf);
            float g_ = tanh_fast(gg);
            float o_ = sigm_f(go);
            float c  = fmaf(f_, c1r[r], i_ * g_);
            c1r[r]   = c;
            h1[b][jj] = o_ * tanh_fast(c);
        }
        __syncthreads();
    }

    // ======== linear head: out[b][o] = h1[b][:50] . W_fc[o][:] + b_fc[o] ========
    if (tid < BB * NOUT) {
        int b = tid >> 2;
        int o = tid & 3;
        float acc = b_fc[o];
#pragma unroll
        for (int k = 0; k < HH; ++k) acc = fmaf(W_fc[o * HH + k], h1[b][k], acc);
        out[(size_t)(b0 + b) * NOUT + o] = acc;
    }
}

extern "C" void kernel_launch(void* const* d_in, const int* in_sizes, int n_in,
                              void* d_out, int out_size, void* d_ws, size_t ws_size,
                              hipStream_t stream) {
    const float* x     = (const float*)d_in[0];
    const float* W_ih0 = (const float*)d_in[1];
    const float* W_hh0 = (const float*)d_in[2];
    const float* b_ih0 = (const float*)d_in[3];
    const float* b_hh0 = (const float*)d_in[4];
    const float* W_ih1 = (const float*)d_in[5];
    const float* W_hh1 = (const float*)d_in[6];
    const float* b_ih1 = (const float*)d_in[7];
    const float* b_hh1 = (const float*)d_in[8];
    const float* W_fc  = (const float*)d_in[9];
    const float* b_fc  = (const float*)d_in[10];
    float* out = (float*)d_out;

    const int B = 4096;
    dim3 grid(B / BB), block(NTHR);
    lstm2_persistent<<<grid, block, 0, stream>>>(
        x, W_ih0, W_hh0, b_ih0, b_hh0, W_ih1, W_hh1, b_ih1, b_hh1, W_fc, b_fc, out);
}

// Round 2
// 5185.814 us; speedup vs baseline: 2.6682x; 2.6682x over previous
//
#include <hip/hip_runtime.h>
#include <math.h>

#define HH   50     // real hidden size
#define HP   64     // padded hidden size
#define GG   256    // padded gate count (4*HP)
#define TT   512    // sequence length
#define BB   16     // batch rows per block
#define NOUT 4
#define NTHR 512
#define KH   28     // k-half width (2*28 = 56 >= 50, float4-granular)

__device__ __forceinline__ float rcp_f(float x) { return __builtin_amdgcn_rcpf(x); }
__device__ __forceinline__ float sigm_f(float x) { return rcp_f(1.0f + __expf(-x)); }
__device__ __forceinline__ float tanh_fast(float x) {
    float ax = fabsf(x);
    float e  = __expf(-2.0f * ax);
    float r  = (1.0f - e) * rcp_f(1.0f + e);
    return copysignf(r, x);
}

__global__ __launch_bounds__(NTHR, 2) void lstm2_splitk(
    const float* __restrict__ x,      // [B, T]
    const float* __restrict__ W_ih0,  // [200, 1]
    const float* __restrict__ W_hh0,  // [200, 50]
    const float* __restrict__ b_ih0,  // [200]
    const float* __restrict__ b_hh0,  // [200]
    const float* __restrict__ W_ih1,  // [200, 50]
    const float* __restrict__ W_hh1,  // [200, 50]
    const float* __restrict__ b_ih1,  // [200]
    const float* __restrict__ b_hh1,  // [200]
    const float* __restrict__ W_fc,   // [4, 50]
    const float* __restrict__ b_fc,   // [4]
    float* __restrict__ out)          // [B, 4]
{
    __shared__ float x_lds[BB][TT];      // 32 KB
    __shared__ float gp[2][BB][GG];      // 64 KB (split-k partials)
    __shared__ float h0[BB][HP];         //  4 KB
    __shared__ float h1[BB][HP];         //  4 KB

    const int tid  = threadIdx.x;
    const int b0   = blockIdx.x * BB;
    const int half = tid >> 8;       // k-half: 0 -> k[0,28), 1 -> k[28,56)
    const int g    = tid & 255;      // padded gate row
    const int type = g >> 6;         // i,f,g,o
    const int j    = g & 63;         // unit within gate type

    // ---- stage x: x_lds[b][t], coalesced global reads, conflict-free writes ----
    for (int i = tid; i < BB * TT; i += NTHR) {
        int bi = i >> 9;        // i / TT
        int ti = i & (TT - 1);  // i % TT
        x_lds[bi][ti] = x[(size_t)(b0 + bi) * TT + ti];
    }
    for (int i = tid; i < BB * HP; i += NTHR) {
        (&h0[0][0])[i] = 0.0f;
        (&h1[0][0])[i] = 0.0f;
    }

    // ---- this thread's half-row weights in registers (84 floats, no spill) ----
    float wA[KH], wB[KH], wC[KH];
    float wx0 = 0.0f, bias0 = 0.0f, bias1 = 0.0f;
#pragma unroll
    for (int kk = 0; kk < KH; ++kk) { wA[kk] = 0.0f; wB[kk] = 0.0f; wC[kk] = 0.0f; }
    if (j < HH) {
        const int gr = type * HH + j;     // real gate row
#pragma unroll
        for (int kk = 0; kk < KH; ++kk) {
            int k = half * KH + kk;
            if (k < HH) {
                wA[kk] = W_hh0[gr * HH + k];
                wB[kk] = W_ih1[gr * HH + k];
                wC[kk] = W_hh1[gr * HH + k];
            }
        }
        if (half == 0) {
            wx0   = W_ih0[gr];
            bias0 = b_ih0[gr] + b_hh0[gr];
            bias1 = b_ih1[gr] + b_hh1[gr];
        }
    }

    // ---- cell state: update unit lin = u*NTHR + tid ----
    float c0r[2], c1r[2];
    c0r[0] = c0r[1] = c1r[0] = c1r[1] = 0.0f;

    __syncthreads();

    for (int t = 0; t < TT; ++t) {
        // ======== layer 0: partial gate pre-activations ========
#pragma unroll 4
        for (int b = 0; b < BB; ++b) {
            const float4* hv = (const float4*)&h0[b][half * KH];
            float ax = 0.f, ay = 0.f, az = 0.f, aw = 0.f;
#pragma unroll
            for (int k4 = 0; k4 < KH / 4; ++k4) {
                float4 hh = hv[k4];                      // wave-broadcast read
                ax = fmaf(wA[4 * k4 + 0], hh.x, ax);
                ay = fmaf(wA[4 * k4 + 1], hh.y, ay);
                az = fmaf(wA[4 * k4 + 2], hh.z, az);
                aw = fmaf(wA[4 * k4 + 3], hh.w, aw);
            }
            float g0 = (ax + ay) + (az + aw);
            if (half == 0) g0 += bias0 + wx0 * x_lds[b][t];   // wave-uniform branch
            gp[half][b][g] = g0;
        }
        __syncthreads();

        // ======== layer 0: pointwise update (1024 units / 512 threads) ========
#pragma unroll
        for (int u = 0; u < 2; ++u) {
            int lin = u * NTHR + tid;
            int b   = lin >> 6;
            int jj  = lin & 63;
            float gi = gp[0][b][jj]       + gp[1][b][jj];
            float gf = gp[0][b][64 + jj]  + gp[1][b][64 + jj];
            float gg = gp[0][b][128 + jj] + gp[1][b][128 + jj];
            float go = gp[0][b][192 + jj] + gp[1][b][192 + jj];
            float i_ = sigm_f(gi);
            float f_ = sigm_f(gf);
            float g_ = tanh_fast(gg);
            float o_ = sigm_f(go);
            float c  = fmaf(f_, c0r[u], i_ * g_);
            c0r[u]   = c;
            h0[b][jj] = o_ * tanh_fast(c);
        }
        __syncthreads();

        // ======== layer 1: partial gate pre-activations ========
#pragma unroll 4
        for (int b = 0; b < BB; ++b) {
            const float4* hav = (const float4*)&h0[b][half * KH];
            const float4* hbv = (const float4*)&h1[b][half * KH];
            float ax = 0.f, ay = 0.f, az = 0.f, aw = 0.f;
#pragma unroll
            for (int k4 = 0; k4 < KH / 4; ++k4) {
                float4 ha = hav[k4];                     // wave-broadcast read
                ax = fmaf(wB[4 * k4 + 0], ha.x, ax);
                ay = fmaf(wB[4 * k4 + 1], ha.y, ay);
                az = fmaf(wB[4 * k4 + 2], ha.z, az);
                aw = fmaf(wB[4 * k4 + 3], ha.w, aw);
                float4 hb = hbv[k4];                     // wave-broadcast read
                ax = fmaf(wC[4 * k4 + 0], hb.x, ax);
                ay = fmaf(wC[4 * k4 + 1], hb.y, ay);
                az = fmaf(wC[4 * k4 + 2], hb.z, az);
                aw = fmaf(wC[4 * k4 + 3], hb.w, aw);
            }
            float g1 = (ax + ay) + (az + aw);
            if (half == 0) g1 += bias1;
            gp[half][b][g] = g1;
        }
        __syncthreads();

        // ======== layer 1: pointwise update ========
#pragma unroll
        for (int u = 0; u < 2; ++u) {
            int lin = u * NTHR + tid;
            int b   = lin >> 6;
            int jj  = lin & 63;
            float gi = gp[0][b][jj]       + gp[1][b][jj];
            float gf = gp[0][b][64 + jj]  + gp[1][b][64 + jj];
            float gg = gp[0][b][128 + jj] + gp[1][b][128 + jj];
            float go = gp[0][b][192 + jj] + gp[1][b][192 + jj];
            float i_ = sigm_f(gi);
            float f_ = sigm_f(gf);
            float g_ = tanh_fast(gg);
            float o_ = sigm_f(go);
            float c  = fmaf(f_, c1r[u], i_ * g_);
            c1r[u]   = c;
            h1[b][jj] = o_ * tanh_fast(c);
        }
        __syncthreads();
    }

    // ======== linear head ========
    if (tid < BB * NOUT) {
        int b = tid >> 2;
        int o = tid & 3;
        float acc = b_fc[o];
#pragma unroll
        for (int k = 0; k < HH; ++k) acc = fmaf(W_fc[o * HH + k], h1[b][k], acc);
        out[(size_t)(b0 + b) * NOUT + o] = acc;
    }
}

extern "C" void kernel_launch(void* const* d_in, const int* in_sizes, int n_in,
                              void* d_out, int out_size, void* d_ws, size_t ws_size,
                              hipStream_t stream) {
    const float* x     = (const float*)d_in[0];
    const float* W_ih0 = (const float*)d_in[1];
    const float* W_hh0 = (const float*)d_in[2];
    const float* b_ih0 = (const float*)d_in[3];
    const float* b_hh0 = (const float*)d_in[4];
    const float* W_ih1 = (const float*)d_in[5];
    const float* W_hh1 = (const float*)d_in[6];
    const float* b_ih1 = (const float*)d_in[7];
    const float* b_hh1 = (const float*)d_in[8];
    const float* W_fc  = (const float*)d_in[9];
    const float* b_fc  = (const float*)d_in[10];
    float* out = (float*)d_out;

    const int B = 4096;
    dim3 grid(B / BB), block(NTHR);
    lstm2_splitk<<<grid, block, 0, stream>>>(
        x, W_ih0, W_hh0, b_ih0, b_hh0, W_ih1, W_hh1, b_ih1, b_hh1, W_fc, b_fc, out);
}

// Round 3
// 419.101 us; speedup vs baseline: 33.0160x; 12.3737x over previous
//
#include <hip/hip_runtime.h>

typedef _Float16 half8 __attribute__((ext_vector_type(8)));
typedef float f32x4 __attribute__((ext_vector_type(4)));

#define TT   512
#define BB   16      // batch rows per block
#define HH   50      // real hidden size
#define NTHR 512     // 8 waves
#define TPW  2       // M-tiles per wave (16 tiles = 256 padded gate rows)
#define LOG2E 1.44269504088896340736f

__device__ __forceinline__ float rcp_f(float x) { return __builtin_amdgcn_rcpf(x); }
// sigmoid, input pre-scaled by log2e: 1/(1+2^-x)
__device__ __forceinline__ float sigm2(float x) {
    return rcp_f(1.0f + __builtin_amdgcn_exp2f(-x));
}
// tanh, input pre-scaled by 2*log2e: 1 - 2/(1+2^x)  (graceful at +-inf)
__device__ __forceinline__ float tanh2(float x) {
    return 1.0f - 2.0f * rcp_f(1.0f + __builtin_amdgcn_exp2f(x));
}

__global__ __launch_bounds__(NTHR, 1) void lstm2_mfma(
    const float* __restrict__ x,      // [B, T]
    const float* __restrict__ W_ih0,  // [200, 1]
    const float* __restrict__ W_hh0,  // [200, 50]
    const float* __restrict__ b_ih0,  // [200]
    const float* __restrict__ b_hh0,  // [200]
    const float* __restrict__ W_ih1,  // [200, 50]
    const float* __restrict__ W_hh1,  // [200, 50]
    const float* __restrict__ b_ih1,  // [200]
    const float* __restrict__ b_hh1,  // [200]
    const float* __restrict__ W_fc,   // [4, 50]
    const float* __restrict__ b_fc,   // [4]
    float* __restrict__ out)          // [B, 4]
{
    // h exchange buffers: [parity][kt][hi][col][8 f16] -> one lane-linear b128 per frag
    __shared__ __align__(16) _Float16 hb0[2][2][4][16][8];   // 4 KB
    __shared__ __align__(16) _Float16 hb1[2][2][4][16][8];   // 4 KB
    __shared__ float x_lds[BB][TT + 8];                      // ~33 KB
    __shared__ float h1f[64][BB + 1];                        // final h1 fp32

    const int tid  = threadIdx.x;
    const int lane = tid & 63;
    const int wid  = tid >> 6;
    const int col  = lane & 15;   // batch col (B-operand n / C col)
    const int hi   = lane >> 4;   // k-group (B) / C row-group
    const int am   = lane & 15;   // A row within tile
    const int ak   = lane >> 4;   // A k-group
    const int b0g  = blockIdx.x * BB;

    // ---- zero h buffers (avoid NaN poison; pads stay 0 forever) ----
    for (int i = tid; i < 2 * 2 * 4 * 16 * 8; i += NTHR) {
        (&hb0[0][0][0][0][0])[i] = (_Float16)0.0f;
        (&hb1[0][0][0][0][0])[i] = (_Float16)0.0f;
    }
    // ---- stage x (coalesced) ----
    for (int it = 0; it < BB * TT / NTHR; ++it) {
        int idx = tid + it * NTHR;
        int bi = idx >> 9, ti = idx & (TT - 1);
        x_lds[bi][ti] = x[(size_t)(b0g + bi) * TT + ti];
    }

    // ---- stationary weight A-frags (f16, gate rows reordered to 4u+type,
    //      rows prescaled: i,f,o by log2e; g by 2*log2e; k zero-padded) ----
    half8 wA[TPW][2], wI[TPW][2], wH[TPW][2];
    f32x4 b0v[TPW], b1v[TPW], wxv[TPW];

    for (int tt = 0; tt < TPW; ++tt) {
        const int tile = wid * TPW + tt;
        const int grow = tile * 16 + am;        // reordered gate row
        const int uu = grow >> 2, ty = grow & 3;
        const float rs = (ty == 2) ? 2.0f * LOG2E : LOG2E;
        const bool ok = (uu < HH);
        const int gsrc = ty * HH + uu;          // original row (i,f,g,o stacked)
        for (int kt = 0; kt < 2; ++kt) {
            half8 a0 = {}, a1 = {}, a2 = {};
            for (int j = 0; j < 8; ++j) {
                int k = kt * 32 + ((j >> 2) << 4) + ak * 4 + (j & 3);
                if (ok && k < HH) {
                    a0[j] = (_Float16)(rs * W_hh0[gsrc * HH + k]);
                    a1[j] = (_Float16)(rs * W_ih1[gsrc * HH + k]);
                    a2[j] = (_Float16)(rs * W_hh1[gsrc * HH + k]);
                }
            }
            wA[tt][kt] = a0; wI[tt][kt] = a1; wH[tt][kt] = a2;
        }
        // bias / wx for the C-layout rows this lane owns (unit u=tile*4+hi, type r)
        f32x4 bb0 = {}, bb1 = {}, wxx = {};
        const int u = tile * 4 + hi;
        if (u < HH) {
            for (int r = 0; r < 4; ++r) {
                float s = (r == 2) ? 2.0f * LOG2E : LOG2E;
                int g = r * HH + u;
                bb0[r] = s * (b_ih0[g] + b_hh0[g]);
                bb1[r] = s * (b_ih1[g] + b_hh1[g]);
                wxx[r] = s * W_ih0[g];
            }
        }
        b0v[tt] = bb0; b1v[tt] = bb1; wxv[tt] = wxx;
    }

    float c0[TPW], c1[TPW];
#pragma unroll
    for (int tt = 0; tt < TPW; ++tt) { c0[tt] = 0.0f; c1[tt] = 0.0f; }

    __syncthreads();

    for (int t = 0; t < TT; ++t) {
        const int pa = t & 1;

        // ---- layer 0: gates = W_hh0 @ h0_prev + bias + wx*x_t ----
        half8 g0k0 = *(const half8*)&hb0[pa][0][hi][col][0];
        half8 g0k1 = *(const half8*)&hb0[pa][1][hi][col][0];
        float xt = x_lds[col][t];
        f32x4 a0[TPW];
#pragma unroll
        for (int tt = 0; tt < TPW; ++tt) a0[tt] = b0v[tt] + wxv[tt] * xt;
#pragma unroll
        for (int tt = 0; tt < TPW; ++tt) {
            a0[tt] = __builtin_amdgcn_mfma_f32_16x16x32_f16(wA[tt][0], g0k0, a0[tt], 0, 0, 0);
            a0[tt] = __builtin_amdgcn_mfma_f32_16x16x32_f16(wA[tt][1], g0k1, a0[tt], 0, 0, 0);
        }
        // ---- layer 0 update (lane-local: regs 0..3 = i,f,g,o of unit u) ----
#pragma unroll
        for (int tt = 0; tt < TPW; ++tt) {
            const int u = (wid * TPW + tt) * 4 + hi;
            float i_ = sigm2(a0[tt][0]);
            float f_ = sigm2(a0[tt][1]);
            float g_ = tanh2(a0[tt][2]);
            float o_ = sigm2(a0[tt][3]);
            float c  = fmaf(f_, c0[tt], i_ * g_);
            c0[tt] = c;
            float h = o_ * tanh2(2.0f * LOG2E * c);
            hb0[pa ^ 1][u >> 5][(u & 15) >> 2][col][(u & 3) | (((u >> 4) & 1) << 2)] = (_Float16)h;
        }
        __syncthreads();   // h0_new visible

        // ---- layer 1: gates = W_ih1 @ h0_new + W_hh1 @ h1_prev + bias ----
        half8 n0k0 = *(const half8*)&hb0[pa ^ 1][0][hi][col][0];
        half8 n0k1 = *(const half8*)&hb0[pa ^ 1][1][hi][col][0];
        half8 o1k0 = *(const half8*)&hb1[pa][0][hi][col][0];
        half8 o1k1 = *(const half8*)&hb1[pa][1][hi][col][0];
        f32x4 a1[TPW];
#pragma unroll
        for (int tt = 0; tt < TPW; ++tt) a1[tt] = b1v[tt];
#pragma unroll
        for (int tt = 0; tt < TPW; ++tt) {
            a1[tt] = __builtin_amdgcn_mfma_f32_16x16x32_f16(wI[tt][0], n0k0, a1[tt], 0, 0, 0);
            a1[tt] = __builtin_amdgcn_mfma_f32_16x16x32_f16(wI[tt][1], n0k1, a1[tt], 0, 0, 0);
            a1[tt] = __builtin_amdgcn_mfma_f32_16x16x32_f16(wH[tt][0], o1k0, a1[tt], 0, 0, 0);
            a1[tt] = __builtin_amdgcn_mfma_f32_16x16x32_f16(wH[tt][1], o1k1, a1[tt], 0, 0, 0);
        }
#pragma unroll
        for (int tt = 0; tt < TPW; ++tt) {
            const int u = (wid * TPW + tt) * 4 + hi;
            float i_ = sigm2(a1[tt][0]);
            float f_ = sigm2(a1[tt][1]);
            float g_ = tanh2(a1[tt][2]);
            float o_ = sigm2(a1[tt][3]);
            float c  = fmaf(f_, c1[tt], i_ * g_);
            c1[tt] = c;
            float h = o_ * tanh2(2.0f * LOG2E * c);
            hb1[pa ^ 1][u >> 5][(u & 15) >> 2][col][(u & 3) | (((u >> 4) & 1) << 2)] = (_Float16)h;
            if (t == TT - 1) h1f[u][col] = h;   // fp32 stash for the head
        }
        __syncthreads();   // h1_new visible / safe to overwrite next step
    }

    // ---- linear head: out[b][o] = h1[b][:50] . W_fc[o][:] + b_fc[o] ----
    if (tid < BB * 4) {
        int b = tid >> 2, o = tid & 3;
        float acc = b_fc[o];
        for (int u = 0; u < HH; ++u) acc = fmaf(W_fc[o * HH + u], h1f[u][b], acc);
        out[(size_t)(b0g + b) * 4 + o] = acc;
    }
}

extern "C" void kernel_launch(void* const* d_in, const int* in_sizes, int n_in,
                              void* d_out, int out_size, void* d_ws, size_t ws_size,
                              hipStream_t stream) {
    const float* x     = (const float*)d_in[0];
    const float* W_ih0 = (const float*)d_in[1];
    const float* W_hh0 = (const float*)d_in[2];
    const float* b_ih0 = (const float*)d_in[3];
    const float* b_hh0 = (const float*)d_in[4];
    const float* W_ih1 = (const float*)d_in[5];
    const float* W_hh1 = (const float*)d_in[6];
    const float* b_ih1 = (const float*)d_in[7];
    const float* b_hh1 = (const float*)d_in[8];
    const float* W_fc  = (const float*)d_in[9];
    const float* b_fc  = (const float*)d_in[10];
    float* out = (float*)d_out;

    const int B = 4096;
    dim3 grid(B / BB), block(NTHR);
    lstm2_mfma<<<grid, block, 0, stream>>>(
        x, W_ih0, W_hh0, b_ih0, b_hh0, W_ih1, W_hh1, b_ih1, b_hh1, W_fc, b_fc, out);
}

// Round 4
// 358.828 us; speedup vs baseline: 38.5617x; 1.1680x over previous
//
#include <hip/hip_runtime.h>

typedef _Float16 half8 __attribute__((ext_vector_type(8)));
typedef float f32x4 __attribute__((ext_vector_type(4)));

#define TT   512
#define BB   16      // batch cols per block
#define HH   50      // real hidden size
#define NTHR 512     // 8 waves
#define TPW  2       // M-tiles per wave (16 tiles = 256 padded gate rows)
#define L2E  1.44269504088896340736f

__device__ __forceinline__ float rcp_f(float x) { return __builtin_amdgcn_rcpf(x); }
__device__ __forceinline__ float exp2_f(float x) { return __builtin_amdgcn_exp2f(x); }

// Fused LSTM cell update, 7 trans ops (4 exp2 + 2 rcp + 1 exp2).
// Preacts prescaled: i,f,o rows by -log2e (so e = 2^{-z*log2e}), g rows by +2log2e.
// sigma(z) = 1/(1+e);  tanh(g) = (eg-1)/(eg+1)
// c' = c*sig(f) + sig(i)*tanh(g) = [c*(1+ei)(eg+1) + (1+ef)(eg-1)] / [(1+ef)(1+ei)(eg+1)]
// h  = sig(o)*tanh(c') = (ec-1) / [(1+eo)(ec+1)],  ec = 2^{2*log2e*c'}
__device__ __forceinline__ float cell_update(f32x4 a, float& c) {
    float ei = exp2_f(a[0]);
    float ef = exp2_f(a[1]);
    float eg = exp2_f(a[2]);
    float eo = exp2_f(a[3]);
    float A  = 1.0f + ei;
    float Bv = 1.0f + ef;
    float G1 = eg + 1.0f;
    float G2 = eg - 1.0f;
    float AG = A * G1;
    float num = fmaf(c, AG, Bv * G2);
    float cn = num * rcp_f(Bv * AG);
    c = cn;
    float ec = exp2_f(cn * (2.0f * L2E));
    return (ec - 1.0f) * rcp_f((1.0f + eo) * (ec + 1.0f));
}

__global__ __launch_bounds__(NTHR, 1) void lstm2_pipe(
    const float* __restrict__ x,      // [B, T]
    const float* __restrict__ W_ih0,  // [200, 1]
    const float* __restrict__ W_hh0,  // [200, 50]
    const float* __restrict__ b_ih0,  // [200]
    const float* __restrict__ b_hh0,  // [200]
    const float* __restrict__ W_ih1,  // [200, 50]
    const float* __restrict__ W_hh1,  // [200, 50]
    const float* __restrict__ b_ih1,  // [200]
    const float* __restrict__ b_hh1,  // [200]
    const float* __restrict__ W_fc,   // [4, 50]
    const float* __restrict__ b_fc,   // [4]
    float* __restrict__ out)          // [B, 4]
{
    // h exchange: [parity][kt][hi][col][8 f16] -> one lane-linear b128 per frag
    __shared__ __align__(16) _Float16 hb0[2][2][4][16][8];   // 4 KB
    __shared__ __align__(16) _Float16 hb1[2][2][4][16][8];   // 4 KB
    __shared__ float x_lds[BB][TT + 10];                     // ~33 KB
    __shared__ float h1f[64][BB + 1];                        // final h1 (fp32)

    const int tid  = threadIdx.x;
    const int lane = tid & 63;
    const int wid  = tid >> 6;
    const int col  = lane & 15;   // batch col
    const int hi   = lane >> 4;
    const int am   = lane & 15;   // A row within tile
    const int ak   = lane >> 4;   // A k-group
    const int b0g  = blockIdx.x * BB;

    // ---- stage x; zero the t=TT pad column ----
    for (int it = 0; it < BB * TT / NTHR; ++it) {
        int idx = tid + it * NTHR;
        int bi = idx >> 9, ti = idx & (TT - 1);
        x_lds[bi][ti] = x[(size_t)(b0g + bi) * TT + ti];
    }
    if (tid < BB) x_lds[tid][TT] = 0.0f;
    // ---- zero both parities of both h buffers ----
    for (int i = tid; i < 1024; i += NTHR) {
        ((unsigned*)hb0)[i] = 0u;
        ((unsigned*)hb1)[i] = 0u;
    }

    // ---- stationary A-frags (f16), gate rows reordered to 4u+type.
    //      Row scales: i,f,o -> -log2e ; g -> +2log2e. k=50 col of W_hh0 carries W_ih0 (x slot).
    half8 wA[TPW][2], wI[TPW][2], wH[TPW][2];
    f32x4 b0v[TPW], b1v[TPW];
    bool  isx[TPW];

    for (int tt = 0; tt < TPW; ++tt) {
        const int tile = wid * TPW + tt;
        const int grow = tile * 16 + am;
        const int uu = grow >> 2, ty = grow & 3;
        const float rs = (ty == 2) ? 2.0f * L2E : -L2E;
        const bool ok = (uu < HH);
        const int gsrc = ty * HH + uu;
        for (int kt = 0; kt < 2; ++kt) {
            half8 a0 = {}, a1 = {}, a2 = {};
            for (int j = 0; j < 8; ++j) {
                int k = kt * 32 + ((j >> 2) << 4) + ak * 4 + (j & 3);
                if (ok) {
                    if (k < HH) {
                        a0[j] = (_Float16)(rs * W_hh0[gsrc * HH + k]);
                        a1[j] = (_Float16)(rs * W_ih1[gsrc * HH + k]);
                        a2[j] = (_Float16)(rs * W_hh1[gsrc * HH + k]);
                    } else if (k == 50) {
                        a0[j] = (_Float16)(rs * W_ih0[gsrc]);   // x rides h0 slot 50
                    }
                }
            }
            wA[tt][kt] = a0; wI[tt][kt] = a1; wH[tt][kt] = a2;
        }
        // fp32 bias via MFMA C-operand (lane owns unit u = tile*4+hi, regs = i,f,g,o)
        f32x4 bb0 = {}, bb1 = {};
        const int u = tile * 4 + hi;
        if (u < HH) {
            for (int r = 0; r < 4; ++r) {
                float s = (r == 2) ? 2.0f * L2E : -L2E;
                int g = r * HH + u;
                bb0[r] = s * (b_ih0[g] + b_hh0[g]);
                bb1[r] = s * (b_ih1[g] + b_hh1[g]);
            }
        }
        b0v[tt] = bb0; b1v[tt] = bb1;
        isx[tt] = (u == 50);   // pad-unit 50 lane carries x_{t+1} into h0 slot 50
    }

    float c0[TPW], c1[TPW];
#pragma unroll
    for (int tt = 0; tt < TPW; ++tt) { c0[tt] = 0.0f; c1[tt] = 0.0f; }

    __syncthreads();
    // seed h0[parity 0] slot 50 with x_0 (after zeroing is barrier-complete)
    if (tid < 16) hb0[0][1][0][tid][6] = (_Float16)x[(size_t)(b0g + tid) * TT];
    __syncthreads();

    // ---- pipelined supersteps: L0 computes t=s (s<TT), L1 computes t=s-1 (1<=s<=TT) ----
    auto step = [&](int s, int p) {
        if (s > TT) { __syncthreads(); return; }
        // h0(s-1) frags: shared input of L0 (state) and L1 (input)
        half8 h0k0 = *(const half8*)&hb0[p][0][hi][col][0];
        half8 h0k1 = *(const half8*)&hb0[p][1][hi][col][0];

        if (s < TT) {   // layer 0, timestep s
            f32x4 acc[TPW];
#pragma unroll
            for (int tt = 0; tt < TPW; ++tt) {
                f32x4 a = __builtin_amdgcn_mfma_f32_16x16x32_f16(wA[tt][0], h0k0, b0v[tt], 0, 0, 0);
                acc[tt] = __builtin_amdgcn_mfma_f32_16x16x32_f16(wA[tt][1], h0k1, a, 0, 0, 0);
            }
#pragma unroll
            for (int tt = 0; tt < TPW; ++tt) {
                float h = cell_update(acc[tt], c0[tt]);
                if (isx[tt]) h = x_lds[col][s + 1];      // slot 50 <- x_{s+1}
                const int u = (wid * TPW + tt) * 4 + hi;
                hb0[p ^ 1][u >> 5][(u & 15) >> 2][col][(u & 3) | (((u >> 4) & 1) << 2)] = (_Float16)h;
            }
        }
        if (s >= 1) {   // layer 1, timestep s-1
            half8 h1k0 = *(const half8*)&hb1[p][0][hi][col][0];
            half8 h1k1 = *(const half8*)&hb1[p][1][hi][col][0];
            f32x4 acc[TPW];
#pragma unroll
            for (int tt = 0; tt < TPW; ++tt) {
                f32x4 a = __builtin_amdgcn_mfma_f32_16x16x32_f16(wI[tt][0], h0k0, b1v[tt], 0, 0, 0);
                a       = __builtin_amdgcn_mfma_f32_16x16x32_f16(wI[tt][1], h0k1, a, 0, 0, 0);
                a       = __builtin_amdgcn_mfma_f32_16x16x32_f16(wH[tt][0], h1k0, a, 0, 0, 0);
                acc[tt] = __builtin_amdgcn_mfma_f32_16x16x32_f16(wH[tt][1], h1k1, a, 0, 0, 0);
            }
#pragma unroll
            for (int tt = 0; tt < TPW; ++tt) {
                float h = cell_update(acc[tt], c1[tt]);
                const int u = (wid * TPW + tt) * 4 + hi;
                hb1[p ^ 1][u >> 5][(u & 15) >> 2][col][(u & 3) | (((u >> 4) & 1) << 2)] = (_Float16)h;
                if (s == TT) h1f[u][col] = h;            // final h1(T-1)
            }
        }
        __syncthreads();
    };

    for (int s = 0; s < TT + 2; s += 2) {
        step(s, 0);
        step(s + 1, 1);
    }

    // ---- linear head: out[b][o] = h1[b][:50] . W_fc[o][:] + b_fc[o] ----
    if (tid < BB * 4) {
        int b = tid >> 2, o = tid & 3;
        float acc = b_fc[o];
        for (int u = 0; u < HH; ++u) acc = fmaf(W_fc[o * HH + u], h1f[u][b], acc);
        out[(size_t)(b0g + b) * 4 + o] = acc;
    }
}

extern "C" void kernel_launch(void* const* d_in, const int* in_sizes, int n_in,
                              void* d_out, int out_size, void* d_ws, size_t ws_size,
                              hipStream_t stream) {
    const float* x     = (const float*)d_in[0];
    const float* W_ih0 = (const float*)d_in[1];
    const float* W_hh0 = (const float*)d_in[2];
    const float* b_ih0 = (const float*)d_in[3];
    const float* b_hh0 = (const float*)d_in[4];
    const float* W_ih1 = (const float*)d_in[5];
    const float* W_hh1 = (const float*)d_in[6];
    const float* b_ih1 = (const float*)d_in[7];
    const float* b_hh1 = (const float*)d_in[8];
    const float* W_fc  = (const float*)d_in[9];
    const float* b_fc  = (const float*)d_in[10];
    float* out = (float*)d_out;

    const int B = 4096;
    dim3 grid(B / BB), block(NTHR);
    lstm2_pipe<<<grid, block, 0, stream>>>(
        x, W_ih0, W_hh0, b_ih0, b_hh0, W_ih1, W_hh1, b_ih1, b_hh1, W_fc, b_fc, out);
}

// Round 5
// 348.981 us; speedup vs baseline: 39.6499x; 1.0282x over previous
//
#include <hip/hip_runtime.h>

typedef _Float16 half8 __attribute__((ext_vector_type(8)));
typedef float f32x4 __attribute__((ext_vector_type(4)));

#define TT   512
#define BB   16      // batch cols per block
#define HH   50      // real hidden size
#define NTHR 1024    // 16 waves, 1 M-tile each
#define L2E  1.44269504088896340736f

__device__ __forceinline__ float rcp_f(float x) { return __builtin_amdgcn_rcpf(x); }
__device__ __forceinline__ float exp2_f(float x) { return __builtin_amdgcn_exp2f(x); }

// Fused LSTM cell update, 7 trans ops (5 exp2 + 2 rcp).
// Preacts prescaled: i,f,o rows by -log2e, g rows by +2log2e.
// c' = [c*(1+ei)(eg+1) + (1+ef)(eg-1)] / [(1+ef)(1+ei)(eg+1)]
// h  = (ec-1) / [(1+eo)(ec+1)],  ec = 2^{2*log2e*c'}
__device__ __forceinline__ float cell_update(f32x4 a, float& c) {
    float ei = exp2_f(a[0]);
    float ef = exp2_f(a[1]);
    float eg = exp2_f(a[2]);
    float eo = exp2_f(a[3]);
    float A  = 1.0f + ei;
    float Bv = 1.0f + ef;
    float G1 = eg + 1.0f;
    float G2 = eg - 1.0f;
    float AG = A * G1;
    float num = fmaf(c, AG, Bv * G2);
    float cn = num * rcp_f(Bv * AG);
    c = cn;
    float ec = exp2_f(cn * (2.0f * L2E));
    return (ec - 1.0f) * rcp_f((1.0f + eo) * (ec + 1.0f));
}

__global__ __launch_bounds__(NTHR, 1) void lstm2_wide(
    const float* __restrict__ x,      // [B, T]
    const float* __restrict__ W_ih0,  // [200, 1]
    const float* __restrict__ W_hh0,  // [200, 50]
    const float* __restrict__ b_ih0,  // [200]
    const float* __restrict__ b_hh0,  // [200]
    const float* __restrict__ W_ih1,  // [200, 50]
    const float* __restrict__ W_hh1,  // [200, 50]
    const float* __restrict__ b_ih1,  // [200]
    const float* __restrict__ b_hh1,  // [200]
    const float* __restrict__ W_fc,   // [4, 50]
    const float* __restrict__ b_fc,   // [4]
    float* __restrict__ out)          // [B, 4]
{
    // h exchange: [parity][kt][hi][col][8 f16] -> one lane-linear b128 per frag
    __shared__ __align__(16) _Float16 hb0[2][2][4][16][8];   // 4 KB
    __shared__ __align__(16) _Float16 hb1[2][2][4][16][8];   // 4 KB
    __shared__ float x_lds[BB][TT + 10];                     // ~33 KB
    __shared__ float h1f[64][BB + 1];                        // final h1 (fp32)

    const int tid  = threadIdx.x;
    const int lane = tid & 63;
    const int wid  = tid >> 6;        // 16 waves; tile = wid
    const int col  = lane & 15;       // batch col
    const int hi   = lane >> 4;
    const int am   = lane & 15;       // A row within tile
    const int ak   = lane >> 4;       // A k-group
    const int b0g  = blockIdx.x * BB;
    const bool active = (wid < 13);   // tiles 13-15 are pure zero padding
    const bool hasx   = (wid == 12);  // tile 12 owns the x slot (u=50)

    // ---- stage x; zero t=TT pad column ----
    for (int it = 0; it < BB * TT / NTHR; ++it) {
        int idx = tid + it * NTHR;
        int bi = idx >> 9, ti = idx & (TT - 1);
        x_lds[bi][ti] = x[(size_t)(b0g + bi) * TT + ti];
    }
    if (tid < BB) x_lds[tid][TT] = 0.0f;
    // ---- zero both parities of both h buffers ----
    for (int i = tid; i < 1024; i += NTHR) {
        ((unsigned*)hb0)[i] = 0u;
        ((unsigned*)hb1)[i] = 0u;
    }

    // ---- stationary A-frags (f16), gate rows reordered to 4u+type.
    //      Row scales: i,f,o -> -log2e ; g -> +2log2e. k=50 of W_hh0 carries W_ih0.
    half8 wA[2], wI[2], wH[2];
    f32x4 b0v = {}, b1v = {};
    {
        const int tile = wid;
        const int grow = tile * 16 + am;
        const int uu = grow >> 2, ty = grow & 3;
        const float rs = (ty == 2) ? 2.0f * L2E : -L2E;
        const bool ok = (uu < HH);
        const int gsrc = ty * HH + uu;
        for (int kt = 0; kt < 2; ++kt) {
            half8 a0 = {}, a1 = {}, a2 = {};
            for (int j = 0; j < 8; ++j) {
                int k = kt * 32 + ((j >> 2) << 4) + ak * 4 + (j & 3);
                if (ok) {
                    if (k < HH) {
                        a0[j] = (_Float16)(rs * W_hh0[gsrc * HH + k]);
                        a1[j] = (_Float16)(rs * W_ih1[gsrc * HH + k]);
                        a2[j] = (_Float16)(rs * W_hh1[gsrc * HH + k]);
                    } else if (k == 50) {
                        a0[j] = (_Float16)(rs * W_ih0[gsrc]);   // x rides h0 slot 50
                    }
                }
            }
            wA[kt] = a0; wI[kt] = a1; wH[kt] = a2;
        }
        const int u = tile * 4 + hi;
        if (u < HH) {
            for (int r = 0; r < 4; ++r) {
                float s = (r == 2) ? 2.0f * L2E : -L2E;
                int g = r * HH + u;
                b0v[r] = s * (b_ih0[g] + b_hh0[g]);
                b1v[r] = s * (b_ih1[g] + b_hh1[g]);
            }
        }
    }
    const int uown = wid * 4 + hi;            // unit this lane updates
    const bool isx = (uown == 50);
    // precomputed h-write slot indices
    const int wkt = uown >> 5;
    const int whi = (uown & 15) >> 2;
    const int wsl = (uown & 3) | (((uown >> 4) & 1) << 2);

    float c0 = 0.0f, c1 = 0.0f;

    __syncthreads();
    if (tid < 16) hb0[0][1][0][tid][6] = (_Float16)x[(size_t)(b0g + tid) * TT];  // x_0 seed
    __syncthreads();

    // ---- pipelined supersteps: L0 computes t=s (s<TT), L1 computes t=s-1 ----
    auto step = [&](int s, int p) {
        if (s <= TT && active) {
            half8 h0k0 = *(const half8*)&hb0[p][0][hi][col][0];
            half8 h0k1 = *(const half8*)&hb0[p][1][hi][col][0];

            if (s < TT) {   // layer 0, timestep s
                f32x4 a = __builtin_amdgcn_mfma_f32_16x16x32_f16(wA[0], h0k0, b0v, 0, 0, 0);
                a       = __builtin_amdgcn_mfma_f32_16x16x32_f16(wA[1], h0k1, a, 0, 0, 0);
                float h = cell_update(a, c0);
                if (hasx) {                                  // slot 50 <- x_{s+1}
                    float xv = x_lds[col][s + 1];
                    h = isx ? xv : h;
                }
                hb0[p ^ 1][wkt][whi][col][wsl] = (_Float16)h;
            }
            if (s >= 1) {   // layer 1, timestep s-1 (two independent 2-deep chains)
                half8 h1k0 = *(const half8*)&hb1[p][0][hi][col][0];
                half8 h1k1 = *(const half8*)&hb1[p][1][hi][col][0];
                f32x4 aA = __builtin_amdgcn_mfma_f32_16x16x32_f16(wI[0], h0k0, b1v, 0, 0, 0);
                aA       = __builtin_amdgcn_mfma_f32_16x16x32_f16(wI[1], h0k1, aA, 0, 0, 0);
                f32x4 aB = {};
                aB       = __builtin_amdgcn_mfma_f32_16x16x32_f16(wH[0], h1k0, aB, 0, 0, 0);
                aB       = __builtin_amdgcn_mfma_f32_16x16x32_f16(wH[1], h1k1, aB, 0, 0, 0);
                f32x4 a  = aA + aB;
                float h = cell_update(a, c1);
                hb1[p ^ 1][wkt][whi][col][wsl] = (_Float16)h;
                if (s == TT) h1f[uown][col] = h;             // final h1(T-1), fp32
            }
        }
        __syncthreads();
    };

    for (int s = 0; s < TT + 2; s += 2) {
        step(s, 0);
        step(s + 1, 1);
    }

    // ---- linear head: out[b][o] = h1[b][:50] . W_fc[o][:] + b_fc[o] ----
    if (tid < BB * 4) {
        int b = tid >> 2, o = tid & 3;
        float acc = b_fc[o];
        for (int u = 0; u < HH; ++u) acc = fmaf(W_fc[o * HH + u], h1f[u][b], acc);
        out[(size_t)(b0g + b) * 4 + o] = acc;
    }
}

extern "C" void kernel_launch(void* const* d_in, const int* in_sizes, int n_in,
                              void* d_out, int out_size, void* d_ws, size_t ws_size,
                              hipStream_t stream) {
    const float* x     = (const float*)d_in[0];
    const float* W_ih0 = (const float*)d_in[1];
    const float* W_hh0 = (const float*)d_in[2];
    const float* b_ih0 = (const float*)d_in[3];
    const float* b_hh0 = (const float*)d_in[4];
    const float* W_ih1 = (const float*)d_in[5];
    const float* W_hh1 = (const float*)d_in[6];
    const float* b_ih1 = (const float*)d_in[7];
    const float* b_hh1 = (const float*)d_in[8];
    const float* W_fc  = (const float*)d_in[9];
    const float* b_fc  = (const float*)d_in[10];
    float* out = (float*)d_out;

    const int B = 4096;
    dim3 grid(B / BB), block(NTHR);
    lstm2_wide<<<grid, block, 0, stream>>>(
        x, W_ih0, W_hh0, b_ih0, b_hh0, W_ih1, W_hh1, b_ih1, b_hh1, W_fc, b_fc, out);
}